// Round 2
// baseline (1149.595 us; speedup 1.0000x reference)
//
#include <hip/hip_runtime.h>
#include <hip/hip_bf16.h>

// ---------------------------------------------------------------------------
// DyadXLSTM forward: x = concat(X, embed[dyad]);  mLSTM(0); sLSTM; mLSTM(1);
// out = x[:, -1, :] @ fc_W + fc_b.
// ALL float tensors are fp32 in memory (per reference); dyad_idx int32.
// B=32 T=256 F=224 E=32 NH=4 DH=64 D=H=256. BT=8192 rows.
// ---------------------------------------------------------------------------

#define BT 8192          // B*T
#define DD 256           // D == H
#define SZ ((size_t)BT * DD)

// ---------------------------------------------------------------------------
// x[b,t,d] = d<224 ? X[b,t,d] : embed[dyad[b], d-224]
__global__ __launch_bounds__(256) void build_x(
    const float* __restrict__ X, const int* __restrict__ dyad,
    const float* __restrict__ embed, float* __restrict__ x)
{
    int i = blockIdx.x * 256 + threadIdx.x;   // over BT*DD
    int d = i & 255;
    int bt = i >> 8;
    int b = bt >> 8;                          // T = 256
    float v;
    if (d < 224) v = X[bt * 224 + d];
    else         v = embed[dyad[b] * 32 + (d - 224)];
    x[i] = v;
}

// ---------------------------------------------------------------------------
// row-wise LayerNorm over D=256, one block per row
__global__ __launch_bounds__(256) void layernorm(
    const float* __restrict__ x, const float* __restrict__ g,
    const float* __restrict__ b, float* __restrict__ xn)
{
    int row = blockIdx.x, tid = threadIdx.x;
    float v = x[(size_t)row * 256 + tid];
    float s = v, s2 = v * v;
    #pragma unroll
    for (int o = 32; o; o >>= 1) { s += __shfl_xor(s, o); s2 += __shfl_xor(s2, o); }
    __shared__ float ls[8];
    int wave = tid >> 6, lane = tid & 63;
    if (lane == 0) { ls[wave] = s; ls[4 + wave] = s2; }
    __syncthreads();
    s  = ls[0] + ls[1] + ls[2] + ls[3];
    s2 = ls[4] + ls[5] + ls[6] + ls[7];
    float mu  = s * (1.f / 256.f);
    float var = s2 * (1.f / 256.f) - mu * mu;
    float inv = rsqrtf(var + 1e-5f);
    xn[(size_t)row * 256 + tid] = (v - mu) * inv * g[tid] + b[tid];
}

// ---------------------------------------------------------------------------
// C[M,N] = alpha * A[M,K](f32) @ W[K,N](f32)  (+ Res[M,N] if non-null)
// 64x64 tile, 4x4 per thread, K staged in chunks of 16.
__global__ __launch_bounds__(256) void gemm_xw(
    const float* __restrict__ A, const float* __restrict__ W,
    const float* __restrict__ Res, float* __restrict__ C,
    int K, int N, float alpha)
{
    __shared__ float Ast[16][68];   // A tile transposed: [k][m]
    __shared__ float Bs[16][68];    // W tile: [k][n]
    const int tid = threadIdx.x;
    const int tx = tid & 15, ty = tid >> 4;
    const int rowBase = blockIdx.x * 64;
    const int colBase = blockIdx.y * 64;
    const int la_r = tid >> 2;          // 0..63
    const int la_c = (tid & 3) << 2;    // 0,4,8,12 (k offset)
    const int lb_k = tid >> 4;          // 0..15
    const int lb_c = (tid & 15) << 2;   // 0..60
    const float* Ap = A + (size_t)(rowBase + la_r) * K + la_c;
    const float* Wp = W + (size_t)lb_k * N + colBase + lb_c;
    float acc[4][4] = {};
    for (int k0 = 0; k0 < K; k0 += 16) {
        float4 a4 = *(const float4*)(Ap + k0);
        float4 w4 = *(const float4*)(Wp + (size_t)k0 * N);
        __syncthreads();
        Ast[la_c + 0][la_r] = a4.x;
        Ast[la_c + 1][la_r] = a4.y;
        Ast[la_c + 2][la_r] = a4.z;
        Ast[la_c + 3][la_r] = a4.w;
        *(float4*)&Bs[lb_k][lb_c] = w4;
        __syncthreads();
        #pragma unroll
        for (int kk = 0; kk < 16; ++kk) {
            float4 av = *(const float4*)&Ast[kk][ty << 2];
            float4 bv = *(const float4*)&Bs[kk][tx << 2];
            acc[0][0] += av.x * bv.x; acc[0][1] += av.x * bv.y;
            acc[0][2] += av.x * bv.z; acc[0][3] += av.x * bv.w;
            acc[1][0] += av.y * bv.x; acc[1][1] += av.y * bv.y;
            acc[1][2] += av.y * bv.z; acc[1][3] += av.y * bv.w;
            acc[2][0] += av.z * bv.x; acc[2][1] += av.z * bv.y;
            acc[2][2] += av.z * bv.z; acc[2][3] += av.z * bv.w;
            acc[3][0] += av.w * bv.x; acc[3][1] += av.w * bv.y;
            acc[3][2] += av.w * bv.z; acc[3][3] += av.w * bv.w;
        }
    }
    #pragma unroll
    for (int i = 0; i < 4; ++i) {
        size_t idx = (size_t)(rowBase + (ty << 2) + i) * N + colBase + (tx << 2);
        float4 v = make_float4(alpha * acc[i][0], alpha * acc[i][1],
                               alpha * acc[i][2], alpha * acc[i][3]);
        if (Res) {
            float4 rv = *(const float4*)(Res + idx);
            v.x += rv.x; v.y += rv.y; v.z += rv.z; v.w += rv.w;
        }
        *(float4*)(C + idx) = v;
    }
}

// ---------------------------------------------------------------------------
// scalar gates: gi/gf[row, h] = xn[row,:] @ W{i,f}[:,h] + b{i,f}[h], NH=4
__global__ __launch_bounds__(256) void gate_gemm(
    const float* __restrict__ xn,
    const float* __restrict__ Wi, const float* __restrict__ Wf,
    const float* __restrict__ bi, const float* __restrict__ bf_,
    float* __restrict__ gi, float* __restrict__ gf)
{
    int tid = threadIdx.x;
    int hh = tid & 3;
    int row = blockIdx.x * 64 + (tid >> 2);
    float ai = bi[hh], af = bf_[hh];
    const float* xr = xn + (size_t)row * 256;
    for (int k = 0; k < 256; ++k) {
        float xv = xr[k];
        ai += xv * Wi[k * 4 + hh];
        af += xv * Wf[k * 4 + hh];
    }
    gi[row * 4 + hh] = ai;
    gf[row * 4 + hh] = af;
}

// ---------------------------------------------------------------------------
// mLSTM recurrence. 1 block = 1 wave = one (b,h). Lane d holds C[d, 0..63].
__global__ __launch_bounds__(64) void mlstm_scan(
    const float* __restrict__ q, const float* __restrict__ k,
    const float* __restrict__ v, const float* __restrict__ o,
    const float* __restrict__ gi, const float* __restrict__ gf,
    float* __restrict__ hout)
{
    int bh = blockIdx.x;
    int b = bh >> 2, h = bh & 3;
    int lane = threadIdx.x;
    float C[64];
    #pragma unroll
    for (int e = 0; e < 64; ++e) C[e] = 0.f;
    float nd = 0.f, m = 0.f;
    __shared__ float kq[128];
    size_t base = (size_t)b * 65536 + h * 64;   // (b*T + t)*256 + h*64
    for (int t = 0; t < 256; ++t) {
        size_t off = base + (size_t)t * 256;
        float qd = q[off + lane], kd = k[off + lane];
        float vd = v[off + lane], od = o[off + lane];
        int gidx = (b * 256 + t) * 4 + h;
        float ipt = gi[gidx], fpt = gf[gidx];
        float mn  = fmaxf(fpt + m, ipt);
        float i_s = __expf(ipt - mn);
        float f_s = __expf(fpt + m - mn);
        m = mn;
        kq[lane] = kd; kq[64 + lane] = qd;
        __syncthreads();
        float iv = i_s * vd;
        float num = 0.f;
        #pragma unroll
        for (int e4 = 0; e4 < 16; ++e4) {
            float4 k4 = ((const float4*)kq)[e4];
            float4 q4 = ((const float4*)(kq + 64))[e4];
            C[e4*4+0] = f_s * C[e4*4+0] + iv * k4.x; num += C[e4*4+0] * q4.x;
            C[e4*4+1] = f_s * C[e4*4+1] + iv * k4.y; num += C[e4*4+1] * q4.y;
            C[e4*4+2] = f_s * C[e4*4+2] + iv * k4.z; num += C[e4*4+2] * q4.z;
            C[e4*4+3] = f_s * C[e4*4+3] + iv * k4.w; num += C[e4*4+3] * q4.w;
        }
        nd = f_s * nd + i_s * kd;
        float pd = nd * qd;
        #pragma unroll
        for (int ofs = 32; ofs; ofs >>= 1) pd += __shfl_xor(pd, ofs);
        float den = fmaxf(fabsf(pd), 1.f);
        float sig = 1.f / (1.f + __expf(-od));
        hout[off + lane] = sig * num / den;
        __syncthreads();
    }
}

// ---------------------------------------------------------------------------
// sLSTM recurrence. 1 block = 4 waves = one (b,h); wave w owns R_w (z,i,f,o),
// holding column e of R_w in 64 registers. State replicated across waves.
__global__ __launch_bounds__(256) void slstm_scan(
    const float* __restrict__ zx, const float* __restrict__ ix,
    const float* __restrict__ fx, const float* __restrict__ ox,
    const float* __restrict__ Rz, const float* __restrict__ Ri,
    const float* __restrict__ Rf, const float* __restrict__ Ro,
    float* __restrict__ hout)
{
    int bh = blockIdx.x;
    int b = bh >> 2, h = bh & 3;
    int wave = threadIdx.x >> 6, e = threadIdx.x & 63;
    const float* R =
        (wave == 0 ? Rz : wave == 1 ? Ri : wave == 2 ? Rf : Ro) + h * 4096;
    float r[64];
    #pragma unroll
    for (int d = 0; d < 64; ++d) r[d] = R[d * 64 + e];
    const float* xin = (wave == 0 ? zx : wave == 1 ? ix : wave == 2 ? fx : ox);
    __shared__ float hl[64];
    __shared__ float gl[4][64];
    if (threadIdx.x < 64) hl[threadIdx.x] = 0.f;
    __syncthreads();
    float c = 0.f, n = 0.f, m = 0.f;
    size_t base = (size_t)b * 65536 + h * 64;
    for (int t = 0; t < 256; ++t) {
        size_t off = base + (size_t)t * 256;
        float g = xin[off + e];
        #pragma unroll
        for (int d4 = 0; d4 < 16; ++d4) {
            float4 h4 = ((const float4*)hl)[d4];
            g += h4.x * r[d4*4+0] + h4.y * r[d4*4+1]
               + h4.z * r[d4*4+2] + h4.w * r[d4*4+3];
        }
        gl[wave][e] = g;
        __syncthreads();
        float zp = gl[0][e], ip = gl[1][e], fp = gl[2][e], op = gl[3][e];
        float z  = tanhf(zp);
        float mn = fmaxf(fp + m, ip);
        float i_s = __expf(ip - mn), f_s = __expf(fp + m - mn);
        m = mn;
        c = f_s * c + i_s * z;
        n = f_s * n + i_s;
        float hv = (1.f / (1.f + __expf(-op))) * c / n;
        if (wave == 0) { hl[e] = hv; hout[off + e] = hv; }
        __syncthreads();
    }
}

// ---------------------------------------------------------------------------
// out[b] = x[b, T-1, :] . fc_W + fc_b   (fp32 out)
__global__ __launch_bounds__(64) void fc_kernel(
    const float* __restrict__ x, const float* __restrict__ fcW,
    const float* __restrict__ fcb, float* __restrict__ out)
{
    int b = blockIdx.x, lane = threadIdx.x;
    const float* xr = x + ((size_t)b * 256 + 255) * 256;
    float s = 0.f;
    #pragma unroll
    for (int j = 0; j < 4; ++j) { int d = j * 64 + lane; s += xr[d] * fcW[d]; }
    #pragma unroll
    for (int ofs = 32; ofs; ofs >>= 1) s += __shfl_xor(s, ofs);
    if (lane == 0) out[b] = s + fcb[0];
}

// ---------------------------------------------------------------------------
extern "C" void kernel_launch(void* const* d_in, const int* in_sizes, int n_in,
                              void* d_out, int out_size, void* d_ws, size_t ws_size,
                              hipStream_t stream)
{
    const float* X      = (const float*)d_in[0];
    const int*   dyad   = (const int*)d_in[1];
    const float* embed  = (const float*)d_in[2];
    const float* m_ln_g = (const float*)d_in[3];
    const float* m_ln_b = (const float*)d_in[4];
    const float* m_Wq   = (const float*)d_in[5];
    const float* m_Wk   = (const float*)d_in[6];
    const float* m_Wv   = (const float*)d_in[7];
    const float* m_Wi   = (const float*)d_in[8];
    const float* m_Wf   = (const float*)d_in[9];
    const float* m_bi   = (const float*)d_in[10];
    const float* m_bf   = (const float*)d_in[11];
    const float* m_Wo   = (const float*)d_in[12];
    const float* m_Wp   = (const float*)d_in[13];
    const float* s_ln_g = (const float*)d_in[14];
    const float* s_ln_b = (const float*)d_in[15];
    const float* s_Wz   = (const float*)d_in[16];
    const float* s_Wi   = (const float*)d_in[17];
    const float* s_Wf   = (const float*)d_in[18];
    const float* s_Wo   = (const float*)d_in[19];
    const float* s_Rz   = (const float*)d_in[20];
    const float* s_Ri   = (const float*)d_in[21];
    const float* s_Rf   = (const float*)d_in[22];
    const float* s_Ro   = (const float*)d_in[23];
    const float* s_Wp   = (const float*)d_in[24];
    const float* fcW    = (const float*)d_in[25];
    const float* fcb    = (const float*)d_in[26];

    float* ws = (float*)d_ws;
    float* x   = ws;            // [BT, 256]
    float* xn  = x  + SZ;       // layernorm out; later reused as scan output hb
    float* g0  = xn + SZ;       // q / z
    float* g1  = g0 + SZ;       // k / i
    float* g2  = g1 + SZ;       // v / f
    float* g3  = g2 + SZ;       // o / o
    float* gi  = g3 + SZ;       // [BT, 4]
    float* gf  = gi + (size_t)BT * 4;
    float* hb  = xn;            // alias: xn dead once the 4/5 GEMMs have run

    dim3 gg(BT / 64, DD / 64);

    build_x<<<8192, 256, 0, stream>>>(X, dyad, embed, x);

    auto mlstm = [&](int L) {
        layernorm<<<BT, 256, 0, stream>>>(x, m_ln_g + L * 256, m_ln_b + L * 256, xn);
        gemm_xw<<<gg, 256, 0, stream>>>(xn, m_Wq + L * 65536, nullptr, g0, 256, 256, 1.0f);
        gemm_xw<<<gg, 256, 0, stream>>>(xn, m_Wk + L * 65536, nullptr, g1, 256, 256, 0.125f);
        gemm_xw<<<gg, 256, 0, stream>>>(xn, m_Wv + L * 65536, nullptr, g2, 256, 256, 1.0f);
        gemm_xw<<<gg, 256, 0, stream>>>(xn, m_Wo + L * 65536, nullptr, g3, 256, 256, 1.0f);
        gate_gemm<<<BT / 64, 256, 0, stream>>>(xn, m_Wi + L * 1024, m_Wf + L * 1024,
                                               m_bi + L * 4, m_bf + L * 4, gi, gf);
        mlstm_scan<<<128, 64, 0, stream>>>(g0, g1, g2, g3, gi, gf, hb);
        gemm_xw<<<gg, 256, 0, stream>>>(hb, m_Wp + L * 65536, x, x, 256, 256, 1.0f);
    };

    mlstm(0);

    layernorm<<<BT, 256, 0, stream>>>(x, s_ln_g, s_ln_b, xn);
    gemm_xw<<<gg, 256, 0, stream>>>(xn, s_Wz, nullptr, g0, 256, 256, 1.0f);
    gemm_xw<<<gg, 256, 0, stream>>>(xn, s_Wi, nullptr, g1, 256, 256, 1.0f);
    gemm_xw<<<gg, 256, 0, stream>>>(xn, s_Wf, nullptr, g2, 256, 256, 1.0f);
    gemm_xw<<<gg, 256, 0, stream>>>(xn, s_Wo, nullptr, g3, 256, 256, 1.0f);
    slstm_scan<<<128, 256, 0, stream>>>(g0, g1, g2, g3, s_Rz, s_Ri, s_Rf, s_Ro, hb);
    gemm_xw<<<gg, 256, 0, stream>>>(hb, s_Wp, x, x, 256, 256, 1.0f);

    mlstm(1);

    fc_kernel<<<32, 64, 0, stream>>>(x, fcW, fcb, (float*)d_out);
}

// Round 4
// 981.155 us; speedup vs baseline: 1.1717x; 1.1717x over previous
//
#include <hip/hip_runtime.h>
#include <hip/hip_bf16.h>

// ---------------------------------------------------------------------------
// DyadXLSTM forward. fp32 in/out; internal: bf16 activations into MFMA GEMMs,
// fp32 state in latency-optimized scans.
// B=32 T=256 NH=4 DH=64 D=H=256, BT=8192.
// ---------------------------------------------------------------------------

#define BT 8192
#define SZ ((size_t)BT * 256)

typedef __attribute__((ext_vector_type(4))) float  f32x4;
typedef __attribute__((ext_vector_type(8))) short  s16x8;

__device__ __forceinline__ float bf2f(unsigned short u) {
    return __uint_as_float(((unsigned int)u) << 16);
}
__device__ __forceinline__ unsigned short f2bf(float f) {
    __hip_bfloat16 h = __float2bfloat16(f);
    return *(unsigned short*)&h;
}

// ---------------------------------------------------------------------------
// Convert+transpose all 15 weight matrices (256x256 fp32, K-major) into
// bf16 Wt[slot][N][K].  slots: 0-4 = mLSTM L0 (q,k,v,o,p), 5-9 = sLSTM
// (z,i,f,o,p), 10-14 = mLSTM L1.
// Each thread stages 16 floats (64x64 tile = 4096 = 256 thr x 16).
__global__ __launch_bounds__(256) void conv_w(
    const float* mWq, const float* mWk, const float* mWv, const float* mWo,
    const float* mWp, const float* sWz, const float* sWi, const float* sWf,
    const float* sWo, const float* sWp, unsigned short* __restrict__ Wt)
{
    int z = blockIdx.z;
    const float* mp[5] = {mWq, mWk, mWv, mWo, mWp};
    const float* sp[5] = {sWz, sWi, sWf, sWo, sWp};
    const float* src;
    if (z < 5)       src = mp[z];
    else if (z < 10) src = sp[z - 5];
    else             src = mp[z - 10] + 65536;
    int kB = blockIdx.x * 64, nB = blockIdx.y * 64;
    __shared__ unsigned short Ts[64][68];
    int tid = threadIdx.x;
    int r = tid >> 2, c = (tid & 3) * 16;       // row 0..63, col {0,16,32,48}
    #pragma unroll
    for (int j = 0; j < 16; j += 4) {
        float4 wv = *(const float4*)(src + (size_t)(kB + r) * 256 + nB + c + j);
        Ts[r][c + j]     = f2bf(wv.x); Ts[r][c + j + 1] = f2bf(wv.y);
        Ts[r][c + j + 2] = f2bf(wv.z); Ts[r][c + j + 3] = f2bf(wv.w);
    }
    __syncthreads();
    int n = tid >> 2, k0 = (tid & 3) * 16;
    __attribute__((aligned(16))) unsigned short tmp[16];
    #pragma unroll
    for (int j = 0; j < 16; ++j) tmp[j] = Ts[k0 + j][n];
    unsigned short* dst = Wt + (size_t)z * 65536 + (size_t)(nB + n) * 256 + kB + k0;
    *(uint4*)dst       = *(const uint4*)tmp;
    *(uint4*)(dst + 8) = *(const uint4*)(tmp + 8);
}

// ---------------------------------------------------------------------------
__global__ __launch_bounds__(256) void build_x(
    const float* __restrict__ X, const int* __restrict__ dyad,
    const float* __restrict__ embed, float* __restrict__ x)
{
    int i = blockIdx.x * 256 + threadIdx.x;
    int d = i & 255, bt = i >> 8, b = bt >> 8;
    x[i] = (d < 224) ? X[bt * 224 + d] : embed[dyad[b] * 32 + (d - 224)];
}

// ---------------------------------------------------------------------------
// LayerNorm over D=256 -> bf16 output (GEMM operand)
__global__ __launch_bounds__(256) void layernorm(
    const float* __restrict__ x, const float* __restrict__ g,
    const float* __restrict__ b, unsigned short* __restrict__ xn)
{
    int row = blockIdx.x, tid = threadIdx.x;
    float v = x[(size_t)row * 256 + tid];
    float s = v, s2 = v * v;
    #pragma unroll
    for (int o = 32; o; o >>= 1) { s += __shfl_xor(s, o); s2 += __shfl_xor(s2, o); }
    __shared__ float ls[8];
    int wave = tid >> 6, lane = tid & 63;
    if (lane == 0) { ls[wave] = s; ls[4 + wave] = s2; }
    __syncthreads();
    s  = ls[0] + ls[1] + ls[2] + ls[3];
    s2 = ls[4] + ls[5] + ls[6] + ls[7];
    float mu  = s * (1.f / 256.f);
    float var = s2 * (1.f / 256.f) - mu * mu;
    float inv = rsqrtf(var + 1e-5f);
    xn[(size_t)row * 256 + tid] = f2bf((v - mu) * inv * g[tid] + b[tid]);
}

// ---------------------------------------------------------------------------
// out[z] = alpha_z * A(bf16) @ W[slot0+z]^T(bf16)  (+Res fp32)
// A:[8192][256] bf16 row-major; Wt[slot]:[N=256][K=256] bf16 (pre-transposed).
// 64x64 tile, 4 waves; wave w does rows 16w..16w+15 x 4 col-tiles of 16.
__global__ __launch_bounds__(256) void gemm_mfma(
    const unsigned short* __restrict__ A, const unsigned short* __restrict__ Wt,
    int slot0, float* out0, const float* Res,
    float a0, float a1, float a2, float a3)
{
    __shared__ unsigned short As[64 * 40];   // [row][k], +8 pad
    __shared__ unsigned short Bs[64 * 40];   // [n][k],  +8 pad
    int tid = threadIdx.x, bz = blockIdx.z;
    const unsigned short* W = Wt + (size_t)(slot0 + bz) * 65536;
    float* out = out0 + (size_t)bz * SZ;
    float alpha = bz == 0 ? a0 : bz == 1 ? a1 : bz == 2 ? a2 : a3;
    int rowBase = blockIdx.x * 64, colBase = blockIdx.y * 64;
    int srow = tid >> 2, scol = (tid & 3) * 8;
    const unsigned short* Ap = A + (size_t)(rowBase + srow) * 256 + scol;
    const unsigned short* Wp = W + (size_t)(colBase + srow) * 256 + scol;
    unsigned short* Asw = As + srow * 40 + scol;
    unsigned short* Bsw = Bs + srow * 40 + scol;
    int w = tid >> 6, lane = tid & 63, quad = lane >> 4, l15 = lane & 15;
    const unsigned short* Ar  = As + (w * 16 + l15) * 40 + quad * 8;
    const unsigned short* Br0 = Bs + l15 * 40 + quad * 8;
    f32x4 acc[4];
    #pragma unroll
    for (int c = 0; c < 4; ++c) acc[c] = (f32x4){0.f, 0.f, 0.f, 0.f};
    for (int k0 = 0; k0 < 256; k0 += 32) {
        uint4 av = *(const uint4*)(Ap + k0);
        uint4 bv = *(const uint4*)(Wp + k0);
        __syncthreads();
        *(uint4*)Asw = av;
        *(uint4*)Bsw = bv;
        __syncthreads();
        s16x8 af = *(const s16x8*)Ar;
        #pragma unroll
        for (int c = 0; c < 4; ++c) {
            s16x8 bf = *(const s16x8*)(Br0 + c * 16 * 40);
            acc[c] = __builtin_amdgcn_mfma_f32_16x16x32_bf16(af, bf, acc[c], 0, 0, 0);
        }
    }
    #pragma unroll
    for (int c = 0; c < 4; ++c) {
        int col  = colBase + c * 16 + l15;
        int row0 = rowBase + w * 16 + quad * 4;
        #pragma unroll
        for (int i2 = 0; i2 < 4; ++i2) {
            size_t idx = (size_t)(row0 + i2) * 256 + col;
            float vv = alpha * acc[c][i2];
            if (Res) vv += Res[idx];
            out[idx] = vv;
        }
    }
}

// ---------------------------------------------------------------------------
// gi/gf[row,h] = xn[row,:].W{i,f}[:,h] + b{i,f}[h]
__global__ __launch_bounds__(256) void gate_gemm(
    const unsigned short* __restrict__ xn,
    const float* __restrict__ Wi, const float* __restrict__ Wf,
    const float* __restrict__ bi, const float* __restrict__ bf_,
    float* __restrict__ gi, float* __restrict__ gf)
{
    int tid = threadIdx.x;
    int hh = tid & 3;
    int row = blockIdx.x * 64 + (tid >> 2);
    float ai = bi[hh], af = bf_[hh];
    const unsigned short* xr = xn + (size_t)row * 256;
    for (int k2 = 0; k2 < 256; ++k2) {
        float xv = bf2f(xr[k2]);
        ai += xv * Wi[k2 * 4 + hh];
        af += xv * Wf[k2 * 4 + hh];
    }
    gi[row * 4 + hh] = ai;
    gf[row * 4 + hh] = af;
}

// ---------------------------------------------------------------------------
// mLSTM scan. Block=(b,h), 4 waves; wave w owns C columns e in [16w,16w+16).
// Lane=d. k/q broadcast via readlane; num partials cross waves via LDS
// (parity double-buffered, ONE barrier per step). n,m,den replicated.
__global__ __launch_bounds__(256) void mlstm_scan(
    const float* __restrict__ q, const float* __restrict__ k,
    const float* __restrict__ v, const float* __restrict__ o,
    const float* __restrict__ gi, const float* __restrict__ gf,
    __hip_bfloat16* __restrict__ hout)
{
    int bh = blockIdx.x, b = bh >> 2, h = bh & 3;
    int tid = threadIdx.x, w = tid >> 6, lane = tid & 63;
    float C[16];
    #pragma unroll
    for (int j = 0; j < 16; ++j) C[j] = 0.f;
    float nd = 0.f, m = 0.f;
    __shared__ float numbuf[2][4][64];
    size_t base = (size_t)b * 65536 + h * 64;
    // prefetch t=0
    float qd = q[base + lane], kd = k[base + lane];
    float vd = v[base + lane], od = o[base + lane];
    float ipt = gi[b * 1024 + h], fpt = gf[b * 1024 + h];
    int eb = w * 16;
    for (int t = 0; t < 256; ++t) {
        float mn  = fmaxf(fpt + m, ipt);
        float i_s = __expf(ipt - mn);
        float f_s = __expf(fpt + m - mn);
        m = mn;
        float iv = i_s * vd;
        float np0 = 0.f, np1 = 0.f;
        #pragma unroll
        for (int j = 0; j < 16; j += 2) {
            float ke0 = __shfl(kd, eb + j),     qe0 = __shfl(qd, eb + j);
            float ke1 = __shfl(kd, eb + j + 1), qe1 = __shfl(qd, eb + j + 1);
            C[j]     = f_s * C[j]     + iv * ke0;  np0 += C[j]     * qe0;
            C[j + 1] = f_s * C[j + 1] + iv * ke1;  np1 += C[j + 1] * qe1;
        }
        nd = f_s * nd + i_s * kd;
        float pd = nd * qd;
        #pragma unroll
        for (int ofs = 32; ofs; ofs >>= 1) pd += __shfl_xor(pd, ofs);
        float den = fmaxf(fabsf(pd), 1.f);
        float sig = 1.f / (1.f + __expf(-od));
        numbuf[t & 1][w][lane] = np0 + np1;
        size_t offc = base + (size_t)t * 256 + lane;
        // prefetch t+1 (before barrier so loads overlap the sync)
        int tn = (t + 1 < 256) ? t + 1 : t;
        size_t offn = base + (size_t)tn * 256 + lane;
        float qn = q[offn], kn = k[offn], vn = v[offn], on = o[offn];
        float ipn = gi[(b * 256 + tn) * 4 + h], fpn = gf[(b * 256 + tn) * 4 + h];
        __syncthreads();
        if (w == 0) {
            float num = numbuf[t & 1][0][lane] + numbuf[t & 1][1][lane]
                      + numbuf[t & 1][2][lane] + numbuf[t & 1][3][lane];
            hout[offc] = __float2bfloat16(sig * num / den);
        }
        qd = qn; kd = kn; vd = vn; od = on; ipt = ipn; fpt = fpn;
    }
}

// ---------------------------------------------------------------------------
// sLSTM scan. Block=(b,h), 4 waves; wave w owns R_w column e in regs.
// h kept in registers (replicated per wave), broadcast via readlane.
// Only gate preacts cross waves: parity-buffered LDS, ONE barrier per step.
__global__ __launch_bounds__(256) void slstm_scan(
    const float* __restrict__ zx, const float* __restrict__ ix,
    const float* __restrict__ fx, const float* __restrict__ ox,
    const float* __restrict__ Rz, const float* __restrict__ Ri,
    const float* __restrict__ Rf, const float* __restrict__ Ro,
    __hip_bfloat16* __restrict__ hout)
{
    int bh = blockIdx.x, b = bh >> 2, h = bh & 3;
    int tid = threadIdx.x, w = tid >> 6, e = tid & 63;
    const float* R = (w == 0 ? Rz : w == 1 ? Ri : w == 2 ? Rf : Ro) + h * 4096;
    float r[64];
    #pragma unroll
    for (int d = 0; d < 64; ++d) r[d] = R[d * 64 + e];
    const float* xin = (w == 0 ? zx : w == 1 ? ix : w == 2 ? fx : ox);
    __shared__ float gl[2][4][64];
    float c = 0.f, n = 0.f, m = 0.f, hv = 0.f;
    size_t base = (size_t)b * 65536 + h * 64 + e;
    float gx = xin[base];
    for (int t = 0; t < 256; ++t) {
        float a0 = 0.f, a1 = 0.f, a2 = 0.f, a3 = 0.f;
        #pragma unroll
        for (int d = 0; d < 64; d += 4) {
            a0 += __shfl(hv, d)     * r[d];
            a1 += __shfl(hv, d + 1) * r[d + 1];
            a2 += __shfl(hv, d + 2) * r[d + 2];
            a3 += __shfl(hv, d + 3) * r[d + 3];
        }
        gl[t & 1][w][e] = gx + ((a0 + a1) + (a2 + a3));
        int tn = (t + 1 < 256) ? t + 1 : t;
        float gxn = xin[base + (size_t)tn * 256];
        __syncthreads();
        float zp = gl[t & 1][0][e], ip = gl[t & 1][1][e];
        float fp = gl[t & 1][2][e], op = gl[t & 1][3][e];
        float ez = __expf(2.f * zp);
        float z  = 1.f - 2.f / (ez + 1.f);          // tanh
        float mn = fmaxf(fp + m, ip);
        float i_s = __expf(ip - mn), f_s = __expf(fp + m - mn);
        m = mn;
        c = f_s * c + i_s * z;
        n = f_s * n + i_s;
        hv = (1.f / (1.f + __expf(-op))) * c / n;
        if (w == 0) hout[base + (size_t)t * 256] = __float2bfloat16(hv);
        gx = gxn;
    }
}

// ---------------------------------------------------------------------------
__global__ __launch_bounds__(64) void fc_kernel(
    const float* __restrict__ x, const float* __restrict__ fcW,
    const float* __restrict__ fcb, float* __restrict__ out)
{
    int b = blockIdx.x, lane = threadIdx.x;
    const float* xr = x + ((size_t)b * 256 + 255) * 256;
    float s = 0.f;
    #pragma unroll
    for (int j = 0; j < 4; ++j) { int d = j * 64 + lane; s += xr[d] * fcW[d]; }
    #pragma unroll
    for (int ofs = 32; ofs; ofs >>= 1) s += __shfl_xor(s, ofs);
    if (lane == 0) out[b] = s + fcb[0];
}

// ---------------------------------------------------------------------------
extern "C" void kernel_launch(void* const* d_in, const int* in_sizes, int n_in,
                              void* d_out, int out_size, void* d_ws, size_t ws_size,
                              hipStream_t stream)
{
    const float* X      = (const float*)d_in[0];
    const int*   dyad   = (const int*)d_in[1];
    const float* embed  = (const float*)d_in[2];
    const float* m_ln_g = (const float*)d_in[3];
    const float* m_ln_b = (const float*)d_in[4];
    const float* m_Wq   = (const float*)d_in[5];
    const float* m_Wk   = (const float*)d_in[6];
    const float* m_Wv   = (const float*)d_in[7];
    const float* m_Wi   = (const float*)d_in[8];
    const float* m_Wf   = (const float*)d_in[9];
    const float* m_bi   = (const float*)d_in[10];
    const float* m_bf   = (const float*)d_in[11];
    const float* m_Wo   = (const float*)d_in[12];
    const float* m_Wp   = (const float*)d_in[13];
    const float* s_ln_g = (const float*)d_in[14];
    const float* s_ln_b = (const float*)d_in[15];
    const float* s_Wz   = (const float*)d_in[16];
    const float* s_Wi   = (const float*)d_in[17];
    const float* s_Wf   = (const float*)d_in[18];
    const float* s_Wo   = (const float*)d_in[19];
    const float* s_Rz   = (const float*)d_in[20];
    const float* s_Ri   = (const float*)d_in[21];
    const float* s_Rf   = (const float*)d_in[22];
    const float* s_Ro   = (const float*)d_in[23];
    const float* s_Wp   = (const float*)d_in[24];
    const float* fcW    = (const float*)d_in[25];
    const float* fcb    = (const float*)d_in[26];

    float* ws = (float*)d_ws;
    float* x  = ws;                       // [8192][256] fp32 residual stream
    float* g0 = x  + SZ;                  // q/z
    float* g1 = g0 + SZ;                  // k/i
    float* g2 = g1 + SZ;                  // v/f
    float* g3 = g2 + SZ;                  // o/o
    float* gi = g3 + SZ;                  // [8192][4]
    float* gf = gi + (size_t)BT * 4;
    unsigned short* xn = (unsigned short*)(gf + (size_t)BT * 4);  // bf16 [8192][256]
    unsigned short* hb = xn + SZ;                                  // bf16 [8192][256]
    unsigned short* Wt = hb + SZ;                                  // bf16 15x[256][256]

    conv_w<<<dim3(4, 4, 15), 256, 0, stream>>>(m_Wq, m_Wk, m_Wv, m_Wo, m_Wp,
                                               s_Wz, s_Wi, s_Wf, s_Wo, s_Wp, Wt);
    build_x<<<8192, 256, 0, stream>>>(X, dyad, embed, x);

    auto mlstm = [&](int L) {
        layernorm<<<BT, 256, 0, stream>>>(x, m_ln_g + L * 256, m_ln_b + L * 256, xn);
        gemm_mfma<<<dim3(128, 4, 4), 256, 0, stream>>>(
            xn, Wt, L * 10, g0, nullptr, 1.f, 0.125f, 1.f, 1.f);
        gate_gemm<<<BT / 64, 256, 0, stream>>>(xn, m_Wi + L * 1024, m_Wf + L * 1024,
                                               m_bi + L * 4, m_bf + L * 4, gi, gf);
        mlstm_scan<<<128, 256, 0, stream>>>(g0, g1, g2, g3, gi, gf,
                                            (__hip_bfloat16*)hb);
        gemm_mfma<<<dim3(128, 4, 1), 256, 0, stream>>>(
            hb, Wt, L * 10 + 4, x, x, 1.f, 1.f, 1.f, 1.f);
    };

    mlstm(0);

    layernorm<<<BT, 256, 0, stream>>>(x, s_ln_g, s_ln_b, xn);
    gemm_mfma<<<dim3(128, 4, 4), 256, 0, stream>>>(
        xn, Wt, 5, g0, nullptr, 1.f, 1.f, 1.f, 1.f);
    slstm_scan<<<128, 256, 0, stream>>>(g0, g1, g2, g3, s_Rz, s_Ri, s_Rf, s_Ro,
                                        (__hip_bfloat16*)hb);
    gemm_mfma<<<dim3(128, 4, 1), 256, 0, stream>>>(
        hb, Wt, 9, x, x, 1.f, 1.f, 1.f, 1.f);

    mlstm(1);

    fc_kernel<<<32, 64, 0, stream>>>(x, fcW, fcb, (float*)d_out);
}

// Round 5
// 370.165 us; speedup vs baseline: 3.1056x; 2.6506x over previous
//
#include <hip/hip_runtime.h>
#include <hip/hip_bf16.h>

// ---------------------------------------------------------------------------
// DyadXLSTM forward. fp32 in/out; bf16 activations into MFMA GEMMs.
// mLSTM recurrence computed as chunked causal attention (exact rewrite):
//   F_t = cumsum(fp), a_t = ip_t - F_t, M_t = max(0, prefix-max a),
//   P_tj = exp(a_j - M_t) * (q_t . k_j)  [j<=t],  h = sig(o) * P V / max(|rowsum P|,1)
// sLSTM stays sequential (nonlinear h feedback), readlane-broadcast matvec.
// B=32 T=256 NH=4 DH=64 D=H=256, BT=8192.
// ---------------------------------------------------------------------------

#define BT 8192
#define SZ ((size_t)BT * 256)

typedef __attribute__((ext_vector_type(4))) float  f32x4;
typedef __attribute__((ext_vector_type(8))) short  s16x8;

__device__ __forceinline__ float bf2f(unsigned short u) {
    return __uint_as_float(((unsigned int)u) << 16);
}
__device__ __forceinline__ unsigned short f2bf(float f) {
    __hip_bfloat16 h = __float2bfloat16(f);
    return *(unsigned short*)&h;
}
__device__ __forceinline__ float rdlane(float v, int l) {
    return __int_as_float(__builtin_amdgcn_readlane(__float_as_int(v), l));
}

// ---------------------------------------------------------------------------
// Convert+transpose 15 weight matrices (256x256 fp32 K-major) -> bf16 Wt[slot][N][K]
__global__ __launch_bounds__(256) void conv_w(
    const float* mWq, const float* mWk, const float* mWv, const float* mWo,
    const float* mWp, const float* sWz, const float* sWi, const float* sWf,
    const float* sWo, const float* sWp, unsigned short* __restrict__ Wt)
{
    int z = blockIdx.z;
    const float* mp[5] = {mWq, mWk, mWv, mWo, mWp};
    const float* sp[5] = {sWz, sWi, sWf, sWo, sWp};
    const float* src;
    if (z < 5)       src = mp[z];
    else if (z < 10) src = sp[z - 5];
    else             src = mp[z - 10] + 65536;
    int kB = blockIdx.x * 64, nB = blockIdx.y * 64;
    __shared__ unsigned short Ts[64][68];
    int tid = threadIdx.x;
    int r = tid >> 2, c = (tid & 3) * 16;
    #pragma unroll
    for (int j = 0; j < 16; j += 4) {
        float4 wv = *(const float4*)(src + (size_t)(kB + r) * 256 + nB + c + j);
        Ts[r][c + j]     = f2bf(wv.x); Ts[r][c + j + 1] = f2bf(wv.y);
        Ts[r][c + j + 2] = f2bf(wv.z); Ts[r][c + j + 3] = f2bf(wv.w);
    }
    __syncthreads();
    int n = tid >> 2, k0 = (tid & 3) * 16;
    __attribute__((aligned(16))) unsigned short tmp[16];
    #pragma unroll
    for (int j = 0; j < 16; ++j) tmp[j] = Ts[k0 + j][n];
    unsigned short* dst = Wt + (size_t)z * 65536 + (size_t)(nB + n) * 256 + kB + k0;
    *(uint4*)dst       = *(const uint4*)tmp;
    *(uint4*)(dst + 8) = *(const uint4*)(tmp + 8);
}

// ---------------------------------------------------------------------------
__global__ __launch_bounds__(256) void build_x(
    const float* __restrict__ X, const int* __restrict__ dyad,
    const float* __restrict__ embed, float* __restrict__ x)
{
    int i = blockIdx.x * 256 + threadIdx.x;
    int d = i & 255, bt = i >> 8, b = bt >> 8;
    x[i] = (d < 224) ? X[bt * 224 + d] : embed[dyad[b] * 32 + (d - 224)];
}

// ---------------------------------------------------------------------------
__global__ __launch_bounds__(256) void layernorm(
    const float* __restrict__ x, const float* __restrict__ g,
    const float* __restrict__ b, unsigned short* __restrict__ xn)
{
    int row = blockIdx.x, tid = threadIdx.x;
    float v = x[(size_t)row * 256 + tid];
    float s = v, s2 = v * v;
    #pragma unroll
    for (int o = 32; o; o >>= 1) { s += __shfl_xor(s, o); s2 += __shfl_xor(s2, o); }
    __shared__ float ls[8];
    int wave = tid >> 6, lane = tid & 63;
    if (lane == 0) { ls[wave] = s; ls[4 + wave] = s2; }
    __syncthreads();
    s  = ls[0] + ls[1] + ls[2] + ls[3];
    s2 = ls[4] + ls[5] + ls[6] + ls[7];
    float mu  = s * (1.f / 256.f);
    float var = s2 * (1.f / 256.f) - mu * mu;
    float inv = rsqrtf(var + 1e-5f);
    xn[(size_t)row * 256 + tid] = f2bf((v - mu) * inv * g[tid] + b[tid]);
}

// ---------------------------------------------------------------------------
// bf16-out GEMM: out[z][8192][256](bf16) = alpha_z * A(bf16) @ Wt[slot0+z]^T
__global__ __launch_bounds__(256) void gemm_mfma_bf16(
    const unsigned short* __restrict__ A, const unsigned short* __restrict__ Wt,
    int slot0, unsigned short* out0, float a0, float a1, float a2, float a3)
{
    __shared__ unsigned short As[64 * 40];
    __shared__ unsigned short Bs[64 * 40];
    int tid = threadIdx.x, bz = blockIdx.z;
    const unsigned short* W = Wt + (size_t)(slot0 + bz) * 65536;
    unsigned short* out = out0 + (size_t)bz * SZ;
    float alpha = bz == 0 ? a0 : bz == 1 ? a1 : bz == 2 ? a2 : a3;
    int rowBase = blockIdx.x * 64, colBase = blockIdx.y * 64;
    int srow = tid >> 2, scol = (tid & 3) * 8;
    const unsigned short* Ap = A + (size_t)(rowBase + srow) * 256 + scol;
    const unsigned short* Wp = W + (size_t)(colBase + srow) * 256 + scol;
    unsigned short* Asw = As + srow * 40 + scol;
    unsigned short* Bsw = Bs + srow * 40 + scol;
    int w = tid >> 6, lane = tid & 63, quad = lane >> 4, l15 = lane & 15;
    const unsigned short* Ar  = As + (w * 16 + l15) * 40 + quad * 8;
    const unsigned short* Br0 = Bs + l15 * 40 + quad * 8;
    f32x4 acc[4];
    #pragma unroll
    for (int c = 0; c < 4; ++c) acc[c] = (f32x4){0.f, 0.f, 0.f, 0.f};
    for (int k0 = 0; k0 < 256; k0 += 32) {
        uint4 av = *(const uint4*)(Ap + k0);
        uint4 bv = *(const uint4*)(Wp + k0);
        __syncthreads();
        *(uint4*)Asw = av;
        *(uint4*)Bsw = bv;
        __syncthreads();
        s16x8 af = *(const s16x8*)Ar;
        #pragma unroll
        for (int c = 0; c < 4; ++c) {
            s16x8 bf = *(const s16x8*)(Br0 + c * 16 * 40);
            acc[c] = __builtin_amdgcn_mfma_f32_16x16x32_bf16(af, bf, acc[c], 0, 0, 0);
        }
    }
    #pragma unroll
    for (int c = 0; c < 4; ++c) {
        int col  = colBase + c * 16 + l15;
        int row0 = rowBase + w * 16 + quad * 4;
        #pragma unroll
        for (int i2 = 0; i2 < 4; ++i2)
            out[(size_t)(row0 + i2) * 256 + col] = f2bf(alpha * acc[c][i2]);
    }
}

// ---------------------------------------------------------------------------
// fp32-out GEMM with residual: out = A(bf16) @ Wt[slot]^T + Res
__global__ __launch_bounds__(256) void gemm_mfma_f32(
    const unsigned short* __restrict__ A, const unsigned short* __restrict__ Wt,
    int slot, float* __restrict__ out, const float* __restrict__ Res)
{
    __shared__ unsigned short As[64 * 40];
    __shared__ unsigned short Bs[64 * 40];
    int tid = threadIdx.x;
    const unsigned short* W = Wt + (size_t)slot * 65536;
    int rowBase = blockIdx.x * 64, colBase = blockIdx.y * 64;
    int srow = tid >> 2, scol = (tid & 3) * 8;
    const unsigned short* Ap = A + (size_t)(rowBase + srow) * 256 + scol;
    const unsigned short* Wp = W + (size_t)(colBase + srow) * 256 + scol;
    unsigned short* Asw = As + srow * 40 + scol;
    unsigned short* Bsw = Bs + srow * 40 + scol;
    int w = tid >> 6, lane = tid & 63, quad = lane >> 4, l15 = lane & 15;
    const unsigned short* Ar  = As + (w * 16 + l15) * 40 + quad * 8;
    const unsigned short* Br0 = Bs + l15 * 40 + quad * 8;
    f32x4 acc[4];
    #pragma unroll
    for (int c = 0; c < 4; ++c) acc[c] = (f32x4){0.f, 0.f, 0.f, 0.f};
    for (int k0 = 0; k0 < 256; k0 += 32) {
        uint4 av = *(const uint4*)(Ap + k0);
        uint4 bv = *(const uint4*)(Wp + k0);
        __syncthreads();
        *(uint4*)Asw = av;
        *(uint4*)Bsw = bv;
        __syncthreads();
        s16x8 af = *(const s16x8*)Ar;
        #pragma unroll
        for (int c = 0; c < 4; ++c) {
            s16x8 bf = *(const s16x8*)(Br0 + c * 16 * 40);
            acc[c] = __builtin_amdgcn_mfma_f32_16x16x32_bf16(af, bf, acc[c], 0, 0, 0);
        }
    }
    #pragma unroll
    for (int c = 0; c < 4; ++c) {
        int col  = colBase + c * 16 + l15;
        int row0 = rowBase + w * 16 + quad * 4;
        #pragma unroll
        for (int i2 = 0; i2 < 4; ++i2) {
            size_t idx = (size_t)(row0 + i2) * 256 + col;
            out[idx] = acc[c][i2] + Res[idx];
        }
    }
}

// ---------------------------------------------------------------------------
// gi/gf[row,h] = xn[row,:].W{i,f}[:,h] + b{i,f}[h]
__global__ __launch_bounds__(256) void gate_gemm(
    const unsigned short* __restrict__ xn,
    const float* __restrict__ Wi, const float* __restrict__ Wf,
    const float* __restrict__ bi, const float* __restrict__ bf_,
    float* __restrict__ gi, float* __restrict__ gf)
{
    int tid = threadIdx.x;
    int hh = tid & 3;
    int row = blockIdx.x * 64 + (tid >> 2);
    float ai = bi[hh], af = bf_[hh];
    const unsigned short* xr = xn + (size_t)row * 256;
    for (int k2 = 0; k2 < 256; ++k2) {
        float xv = bf2f(xr[k2]);
        ai += xv * Wi[k2 * 4 + hh];
        af += xv * Wf[k2 * 4 + hh];
    }
    gi[row * 4 + hh] = ai;
    gf[row * 4 + hh] = af;
}

// ---------------------------------------------------------------------------
// Per-(b,h): F = cumsum(fp); a = ip - F; M = max(0, prefix-max(a)).
// One block per bh, thread = t, Hillis-Steele scans in LDS.
__global__ __launch_bounds__(256) void scan_am(
    const float* __restrict__ gi, const float* __restrict__ gf,
    float* __restrict__ a_arr, float* __restrict__ M_arr)
{
    int bh = blockIdx.x, b = bh >> 2, h = bh & 3;
    int t = threadIdx.x;
    float fp = gf[(b * 256 + t) * 4 + h];
    float ip = gi[(b * 256 + t) * 4 + h];
    __shared__ float buf[256];
    buf[t] = fp;
    __syncthreads();
    #pragma unroll
    for (int o = 1; o < 256; o <<= 1) {
        float add = (t >= o) ? buf[t - o] : 0.f;
        __syncthreads();
        buf[t] += add;
        __syncthreads();
    }
    float F = buf[t];
    float a = ip - F;
    __syncthreads();
    buf[t] = a;
    __syncthreads();
    #pragma unroll
    for (int o = 1; o < 256; o <<= 1) {
        float mx = (t >= o) ? buf[t - o] : -3.4e38f;
        __syncthreads();
        buf[t] = fmaxf(buf[t], mx);
        __syncthreads();
    }
    a_arr[bh * 256 + t] = a;
    M_arr[bh * 256 + t] = fmaxf(buf[t], 0.f);
}

// ---------------------------------------------------------------------------
// mLSTM as causal decay-attention. Block = (bh, row-tile rt of 64).
// 4 waves; wave w owns rows [16w,16w+16) of the row tile.
__global__ __launch_bounds__(256) void mlstm_attn(
    const unsigned short* __restrict__ qb, const unsigned short* __restrict__ kb,
    const unsigned short* __restrict__ vb, const unsigned short* __restrict__ ob,
    const float* __restrict__ a_arr, const float* __restrict__ M_arr,
    unsigned short* __restrict__ hout)
{
    int bh = blockIdx.x, rt = blockIdx.y;
    int b = bh >> 2, h = bh & 3;
    int tid = threadIdx.x, w = tid >> 6, lane = tid & 63;
    int quad = lane >> 4, l15 = lane & 15;
    __shared__ unsigned short Qs[64][72];
    __shared__ unsigned short Ks[64][72];
    __shared__ unsigned short Vt[64][72];      // V transposed: [d][j]
    __shared__ unsigned short Ps[4][16][72];   // per-wave P strip
    __shared__ float a_s[64], M_s[64];
    int sr = tid >> 2, sc = (tid & 3) * 16;
    size_t qoff = (size_t)(b * 256 + rt * 64 + sr) * 256 + h * 64 + sc;
    *(uint4*)&Qs[sr][sc]     = *(const uint4*)(qb + qoff);
    *(uint4*)&Qs[sr][sc + 8] = *(const uint4*)(qb + qoff + 8);
    if (tid < 64) M_s[tid] = M_arr[bh * 256 + rt * 64 + tid];
    f32x4 accN[4];
    #pragma unroll
    for (int c = 0; c < 4; ++c) accN[c] = (f32x4){0.f, 0.f, 0.f, 0.f};
    f32x4 den = (f32x4){0.f, 0.f, 0.f, 0.f};
    int rowT = w * 16 + quad * 4;              // row within 64-tile (+i2)
    for (int ct = 0; ct <= rt; ++ct) {
        // stage K, V^T, a for this j-tile
        size_t koff = (size_t)(b * 256 + ct * 64 + sr) * 256 + h * 64 + sc;
        uint4 kv0 = *(const uint4*)(kb + koff);
        uint4 kv1 = *(const uint4*)(kb + koff + 8);
        uint4 vv0 = *(const uint4*)(vb + koff);
        uint4 vv1 = *(const uint4*)(vb + koff + 8);
        *(uint4*)&Ks[sr][sc]     = kv0;
        *(uint4*)&Ks[sr][sc + 8] = kv1;
        __attribute__((aligned(16))) unsigned short vt[16];
        *(uint4*)vt = vv0; *(uint4*)(vt + 8) = vv1;
        #pragma unroll
        for (int jj = 0; jj < 16; ++jj) Vt[sc + jj][sr] = vt[jj];
        if (tid < 64) a_s[tid] = a_arr[bh * 256 + ct * 64 + tid];
        __syncthreads();
        // S = Q K^T (16x64 strip per wave)
        f32x4 S[4];
        #pragma unroll
        for (int c = 0; c < 4; ++c) S[c] = (f32x4){0.f, 0.f, 0.f, 0.f};
        #pragma unroll
        for (int ks = 0; ks < 2; ++ks) {
            s16x8 af = *(const s16x8*)&Qs[w * 16 + l15][quad * 8 + ks * 32];
            #pragma unroll
            for (int c = 0; c < 4; ++c) {
                s16x8 bfr = *(const s16x8*)&Ks[c * 16 + l15][quad * 8 + ks * 32];
                S[c] = __builtin_amdgcn_mfma_f32_16x16x32_bf16(af, bfr, S[c], 0, 0, 0);
            }
        }
        // scale by exp(a_j - M_t), causal mask on diagonal tile, rowsum
        bool dg = (ct == rt);
        #pragma unroll
        for (int c = 0; c < 4; ++c) {
            int col = c * 16 + l15;
            #pragma unroll
            for (int i2 = 0; i2 < 4; ++i2) {
                int row = rowT + i2;
                float p = S[c][i2] * __expf(a_s[col] - M_s[row]);
                if (dg && col > row) p = 0.f;
                S[c][i2] = p;
                den[i2] += p;
            }
        }
        // P -> LDS (bf16) for A-fragment relayout
        #pragma unroll
        for (int c = 0; c < 4; ++c)
            #pragma unroll
            for (int i2 = 0; i2 < 4; ++i2)
                Ps[w][quad * 4 + i2][c * 16 + l15] = f2bf(S[c][i2]);
        __syncthreads();
        // num += P V
        #pragma unroll
        for (int ks = 0; ks < 2; ++ks) {
            s16x8 af = *(const s16x8*)&Ps[w][l15][quad * 8 + ks * 32];
            #pragma unroll
            for (int c = 0; c < 4; ++c) {
                s16x8 bfr = *(const s16x8*)&Vt[c * 16 + l15][quad * 8 + ks * 32];
                accN[c] = __builtin_amdgcn_mfma_f32_16x16x32_bf16(af, bfr, accN[c], 0, 0, 0);
            }
        }
        __syncthreads();
    }
    // reduce den across the 16 lanes sharing rows (l15 dimension)
    #pragma unroll
    for (int ofs = 1; ofs < 16; ofs <<= 1) {
        den[0] += __shfl_xor(den[0], ofs);
        den[1] += __shfl_xor(den[1], ofs);
        den[2] += __shfl_xor(den[2], ofs);
        den[3] += __shfl_xor(den[3], ofs);
    }
    // epilogue: h = sigmoid(o) * num / max(|den|,1)
    #pragma unroll
    for (int c = 0; c < 4; ++c) {
        int d = c * 16 + l15;
        #pragma unroll
        for (int i2 = 0; i2 < 4; ++i2) {
            size_t idx = (size_t)(b * 256 + rt * 64 + rowT + i2) * 256 + h * 64 + d;
            float ov = bf2f(ob[idx]);
            float sg = 1.f / (1.f + __expf(-ov));
            float dn = fmaxf(fabsf(den[i2]), 1.f);
            hout[idx] = f2bf(sg * accN[c][i2] / dn);
        }
    }
}

// ---------------------------------------------------------------------------
// sLSTM scan. Block=(b,h), 4 waves; wave w owns R_w column e in regs.
// h replicated per wave; broadcast via v_readlane (no LDS for h).
__global__ __launch_bounds__(256) void slstm_scan(
    const unsigned short* __restrict__ zx, const unsigned short* __restrict__ ix,
    const unsigned short* __restrict__ fx, const unsigned short* __restrict__ ox,
    const float* __restrict__ Rz, const float* __restrict__ Ri,
    const float* __restrict__ Rf, const float* __restrict__ Ro,
    unsigned short* __restrict__ hout)
{
    int bh = blockIdx.x, b = bh >> 2, h = bh & 3;
    int tid = threadIdx.x, w = tid >> 6, e = tid & 63;
    const float* R = (w == 0 ? Rz : w == 1 ? Ri : w == 2 ? Rf : Ro) + h * 4096;
    float r[64];
    #pragma unroll
    for (int d = 0; d < 64; ++d) r[d] = R[d * 64 + e];
    const unsigned short* xin = (w == 0 ? zx : w == 1 ? ix : w == 2 ? fx : ox);
    __shared__ float gl[2][4][64];
    float c = 0.f, n = 0.f, m = 0.f, hv = 0.f;
    size_t base = (size_t)b * 65536 + h * 64 + e;
    float gx = bf2f(xin[base]);
    for (int t = 0; t < 256; ++t) {
        float a0 = 0.f, a1 = 0.f, a2 = 0.f, a3 = 0.f;
        #pragma unroll
        for (int d = 0; d < 64; d += 4) {
            a0 += rdlane(hv, d)     * r[d];
            a1 += rdlane(hv, d + 1) * r[d + 1];
            a2 += rdlane(hv, d + 2) * r[d + 2];
            a3 += rdlane(hv, d + 3) * r[d + 3];
        }
        gl[t & 1][w][e] = gx + ((a0 + a1) + (a2 + a3));
        int tn = (t + 1 < 256) ? t + 1 : t;
        float gxn = bf2f(xin[base + (size_t)tn * 256]);
        __syncthreads();
        float zp = gl[t & 1][0][e], ip = gl[t & 1][1][e];
        float fp = gl[t & 1][2][e], op = gl[t & 1][3][e];
        float ez = __expf(2.f * zp);
        float z  = 1.f - 2.f / (ez + 1.f);          // tanh
        float mn = fmaxf(fp + m, ip);
        float i_s = __expf(ip - mn), f_s = __expf(fp + m - mn);
        m = mn;
        c = f_s * c + i_s * z;
        n = f_s * n + i_s;
        hv = (1.f / (1.f + __expf(-op))) * c / n;
        if (w == 0) hout[base + (size_t)t * 256] = f2bf(hv);
        gx = gxn;
    }
}

// ---------------------------------------------------------------------------
__global__ __launch_bounds__(64) void fc_kernel(
    const float* __restrict__ x, const float* __restrict__ fcW,
    const float* __restrict__ fcb, float* __restrict__ out)
{
    int b = blockIdx.x, lane = threadIdx.x;
    const float* xr = x + ((size_t)b * 256 + 255) * 256;
    float s = 0.f;
    #pragma unroll
    for (int j = 0; j < 4; ++j) { int d = j * 64 + lane; s += xr[d] * fcW[d]; }
    #pragma unroll
    for (int ofs = 32; ofs; ofs >>= 1) s += __shfl_xor(s, ofs);
    if (lane == 0) out[b] = s + fcb[0];
}

// ---------------------------------------------------------------------------
extern "C" void kernel_launch(void* const* d_in, const int* in_sizes, int n_in,
                              void* d_out, int out_size, void* d_ws, size_t ws_size,
                              hipStream_t stream)
{
    const float* X      = (const float*)d_in[0];
    const int*   dyad   = (const int*)d_in[1];
    const float* embed  = (const float*)d_in[2];
    const float* m_ln_g = (const float*)d_in[3];
    const float* m_ln_b = (const float*)d_in[4];
    const float* m_Wq   = (const float*)d_in[5];
    const float* m_Wk   = (const float*)d_in[6];
    const float* m_Wv   = (const float*)d_in[7];
    const float* m_Wi   = (const float*)d_in[8];
    const float* m_Wf   = (const float*)d_in[9];
    const float* m_bi   = (const float*)d_in[10];
    const float* m_bf   = (const float*)d_in[11];
    const float* m_Wo   = (const float*)d_in[12];
    const float* m_Wp   = (const float*)d_in[13];
    const float* s_ln_g = (const float*)d_in[14];
    const float* s_ln_b = (const float*)d_in[15];
    const float* s_Wz   = (const float*)d_in[16];
    const float* s_Wi   = (const float*)d_in[17];
    const float* s_Wf   = (const float*)d_in[18];
    const float* s_Wo   = (const float*)d_in[19];
    const float* s_Rz   = (const float*)d_in[20];
    const float* s_Ri   = (const float*)d_in[21];
    const float* s_Rf   = (const float*)d_in[22];
    const float* s_Ro   = (const float*)d_in[23];
    const float* s_Wp   = (const float*)d_in[24];
    const float* fcW    = (const float*)d_in[25];
    const float* fcb    = (const float*)d_in[26];

    float* ws = (float*)d_ws;
    float* x     = ws;                         // fp32 [8192][256]
    float* gi    = x + SZ;                     // fp32 [8192][4]
    float* gf    = gi + (size_t)BT * 4;
    float* a_arr = gf + (size_t)BT * 4;        // fp32 [128][256]
    float* M_arr = a_arr + 32768;
    unsigned short* xn  = (unsigned short*)(M_arr + 32768);  // bf16 [8192][256]
    unsigned short* hb  = xn + SZ;
    unsigned short* g0u = hb + SZ;             // q/z
    unsigned short* g1u = g0u + SZ;            // k/i
    unsigned short* g2u = g1u + SZ;            // v/f
    unsigned short* g3u = g2u + SZ;            // o/o
    unsigned short* Wt  = g3u + SZ;            // bf16 15x[256][256]

    conv_w<<<dim3(4, 4, 15), 256, 0, stream>>>(m_Wq, m_Wk, m_Wv, m_Wo, m_Wp,
                                               s_Wz, s_Wi, s_Wf, s_Wo, s_Wp, Wt);
    build_x<<<8192, 256, 0, stream>>>(X, dyad, embed, x);

    dim3 gg(128, 4);

    auto mlstm = [&](int L) {
        layernorm<<<BT, 256, 0, stream>>>(x, m_ln_g + L * 256, m_ln_b + L * 256, xn);
        gemm_mfma_bf16<<<dim3(128, 4, 4), 256, 0, stream>>>(
            xn, Wt, L * 10, g0u, 1.f, 0.125f, 1.f, 1.f);
        gate_gemm<<<BT / 64, 256, 0, stream>>>(xn, m_Wi + L * 1024, m_Wf + L * 1024,
                                               m_bi + L * 4, m_bf + L * 4, gi, gf);
        scan_am<<<128, 256, 0, stream>>>(gi, gf, a_arr, M_arr);
        mlstm_attn<<<gg, 256, 0, stream>>>(g0u, g1u, g2u, g3u, a_arr, M_arr, hb);
        gemm_mfma_f32<<<dim3(128, 4, 1), 256, 0, stream>>>(hb, Wt, L * 10 + 4, x, x);
    };

    mlstm(0);

    layernorm<<<BT, 256, 0, stream>>>(x, s_ln_g, s_ln_b, xn);
    gemm_mfma_bf16<<<dim3(128, 4, 4), 256, 0, stream>>>(
        xn, Wt, 5, g0u, 1.f, 1.f, 1.f, 1.f);
    slstm_scan<<<128, 256, 0, stream>>>(g0u, g1u, g2u, g3u,
                                        s_Rz, s_Ri, s_Rf, s_Ro, hb);
    gemm_mfma_f32<<<dim3(128, 4, 1), 256, 0, stream>>>(hb, Wt, 9, x, x);

    mlstm(1);

    fc_kernel<<<32, 64, 0, stream>>>(x, fcW, fcb, (float*)d_out);
}